// Round 8
// baseline (70.497 us; speedup 1.0000x reference)
//
#include <hip/hip_runtime.h>

#define HH 4096
#define WW 4096
#define MAXK (1 << 20)      // == NRS * 16
#define NSP 16              // 256-px spans per row
#define SPW 256             // span width
#define NRS (HH * NSP)      // 65536 row-spans (1 per wave)
#define NBLK (NRS / 4)      // 16384 blocks, 4 waves each

typedef int   v4i __attribute__((ext_vector_type(4)));
typedef float v4f __attribute__((ext_vector_type(4)));

// ---------------------------------------------------------------------------
// Kernel 1: 3x3 NMS. One WAVE per 256-px row-span; lane owns 4 contiguous px.
// 5 streams/wave (repU/repC/repD/rel + mx), shuffle halo, no LDS, no barriers.
// Clamp-to-edge == -inf SAME padding for a max filter.
// XCD swizzle: 2048 consecutive blocks (512 rows) per XCD -> rep-row reuse
// across vertical neighbors stays in one XCD's L2.
// ---------------------------------------------------------------------------
__global__ __launch_bounds__(256, 8) void k_maxima(
    const float* __restrict__ rel, const float* __restrict__ rep,
    int* __restrict__ mx, unsigned char* __restrict__ masks,
    int* __restrict__ counts)
{
    const int tid  = threadIdx.x;
    const int lane = tid & 63;
    const int swz  = (blockIdx.x & 7) * (NBLK / 8) + (blockIdx.x >> 3);
    const int rs   = swz * 4 + (tid >> 6);     // row-span id, 0..NRS-1
    const int y    = rs >> 4;
    const int span = rs & (NSP - 1);
    const int x0   = span * SPW + lane * 4;

    const int xl = span ? span * SPW - 1 : 0;                    // left halo col
    const int xr = (span < NSP - 1) ? (span + 1) * SPW : WW - 1; // right halo col
    const int hx = (lane == 63) ? xr : xl;     // 2 cache lines, broadcast

    const float* rowC = rep + (size_t)y * WW;
    const float* rowU = rep + (size_t)(y > 0      ? y - 1 : 0     ) * WW;
    const float* rowD = rep + (size_t)(y < HH - 1 ? y + 1 : HH - 1) * WW;

    const v4f U = *reinterpret_cast<const v4f*>(rowU + x0);
    const v4f C = *reinterpret_cast<const v4f*>(rowC + x0);
    const v4f D = *reinterpret_cast<const v4f*>(rowD + x0);
    const v4f V = __builtin_nontemporal_load(
        reinterpret_cast<const v4f*>(rel + (size_t)y * WW + x0));
    const float hu = rowU[hx], hc = rowC[hx], hd = rowD[hx];

    // vertical 3-max
    const float vm0 = fmaxf(fmaxf(U.x, C.x), D.x);
    const float vm1 = fmaxf(fmaxf(U.y, C.y), D.y);
    const float vm2 = fmaxf(fmaxf(U.z, C.z), D.z);
    const float vm3 = fmaxf(fmaxf(U.w, C.w), D.w);
    const float hvm = fmaxf(fmaxf(hu, hc), hd);

    // horizontal halo via wave shuffles
    float left  = __shfl_up(vm3, 1, 64);
    float right = __shfl_down(vm0, 1, 64);
    if (lane == 0)  left  = hvm;
    if (lane == 63) right = hvm;

    const float m30 = fmaxf(fmaxf(left, vm0), vm1);
    const float m31 = fmaxf(fmaxf(vm0, vm1), vm2);
    const float m32 = fmaxf(fmaxf(vm1, vm2), vm3);
    const float m33 = fmaxf(fmaxf(vm2, vm3), right);

    unsigned int mask = 0;
    if (C.x == m30 && C.x >= 0.7f && V.x >= 0.7f) mask |= 1u;
    if (C.y == m31 && C.y >= 0.7f && V.y >= 0.7f) mask |= 2u;
    if (C.z == m32 && C.z >= 0.7f && V.z >= 0.7f) mask |= 4u;
    if (C.w == m33 && C.w >= 0.7f && V.w >= 0.7f) mask |= 8u;

    // maxima as int32 0/1, lane-contiguous, nontemporal (write-once)
    v4i o;
    o.x = mask & 1u;        o.y = (mask >> 1) & 1u;
    o.z = (mask >> 2) & 1u; o.w = (mask >> 3) & 1u;
    __builtin_nontemporal_store(o,
        reinterpret_cast<v4i*>(mx + (size_t)y * WW + x0));

    if (masks) masks[(size_t)rs * 64 + lane] = (unsigned char)mask;

    const int cnt = __popcll(__ballot(mask & 1u)) + __popcll(__ballot(mask & 2u))
                  + __popcll(__ballot(mask & 4u)) + __popcll(__ballot(mask & 8u));
    if (lane == 0) counts[rs] = cnt;
}

// ---------------------------------------------------------------------------
// Kernel 2: exclusive scan of 65536 row-span counts. One block, 1024 threads,
// 64 counts/thread. offsets[NRS] = total.
// ---------------------------------------------------------------------------
__global__ __launch_bounds__(1024) void k_scan(const int* __restrict__ counts,
                                               int* __restrict__ offsets)
{
    const int tid  = threadIdx.x;
    const int lane = tid & 63, wid = tid >> 6;   // 16 waves

    int v[64];
    int tot = 0;
    const int4* src = reinterpret_cast<const int4*>(counts + tid * 64);
#pragma unroll
    for (int i = 0; i < 16; ++i) {
        int4 a = src[i];
        v[4 * i] = a.x; v[4 * i + 1] = a.y; v[4 * i + 2] = a.z; v[4 * i + 3] = a.w;
        tot += a.x + a.y + a.z + a.w;
    }

    int inc = tot;
#pragma unroll
    for (int off = 1; off < 64; off <<= 1) {
        int n = __shfl_up(inc, off, 64);
        if (lane >= off) inc += n;
    }
    __shared__ int wsum[16];
    if (lane == 63) wsum[wid] = inc;
    __syncthreads();
    int wbase = 0;
    for (int w = 0; w < wid; ++w) wbase += wsum[w];

    int run = wbase + inc - tot;
    int4* dst = reinterpret_cast<int4*>(offsets + tid * 64);
#pragma unroll
    for (int i = 0; i < 16; ++i) {
        int4 o;
        o.x = run; run += v[4 * i];
        o.y = run; run += v[4 * i + 1];
        o.z = run; run += v[4 * i + 2];
        o.w = run; run += v[4 * i + 3];
        dst[i] = o;
    }
    if (tid == 1023) offsets[NRS] = run;   // total keypoint count
}

// ---------------------------------------------------------------------------
// Kernel 3a: ordered compaction, one WAVE per row-span, no LDS/barriers.
// Fused -1 tail fill: row-span rs owns coord slots [rs*16, rs*16+16).
// ---------------------------------------------------------------------------
__global__ __launch_bounds__(256) void k_emit_ws(
    const unsigned char* __restrict__ masks, const int* __restrict__ offsets,
    int* __restrict__ oy, int* __restrict__ ox)
{
    const int tid  = threadIdx.x;
    const int lane = tid & 63;
    const int rs   = blockIdx.x * 4 + (tid >> 6);

    const int total = offsets[NRS];
    if (lane < 16) {
        const int slot = rs * 16 + lane;
        if (slot >= total) { oy[slot] = -1; ox[slot] = -1; }
    }

    unsigned int mask = masks[(size_t)rs * 64 + lane];

    const int cnt = __popc(mask);
    int inc = cnt;
#pragma unroll
    for (int off = 1; off < 64; off <<= 1) {
        int n = __shfl_up(inc, off, 64);
        if (lane >= off) inc += n;
    }

    int pos = offsets[rs] + inc - cnt;
    const int y  = rs >> 4;
    const int xb = (rs & (NSP - 1)) * SPW + lane * 4;
    while (mask) {
        int b = __ffs(mask) - 1;
        mask &= mask - 1;
        if (pos < MAXK) { oy[pos] = y; ox[pos] = xb + b; }
        ++pos;
    }
}

// ---------------------------------------------------------------------------
// Kernel 3b: fallback — rebuild masks from the int32 maxima array.
// ---------------------------------------------------------------------------
__global__ __launch_bounds__(256) void k_emit_mx(
    const int* __restrict__ mx, const int* __restrict__ offsets,
    int* __restrict__ oy, int* __restrict__ ox)
{
    const int tid  = threadIdx.x;
    const int lane = tid & 63;
    const int rs   = blockIdx.x * 4 + (tid >> 6);

    const int total = offsets[NRS];
    if (lane < 16) {
        const int slot = rs * 16 + lane;
        if (slot >= total) { oy[slot] = -1; ox[slot] = -1; }
    }

    const int y  = rs >> 4;
    const int xb = (rs & (NSP - 1)) * SPW + lane * 4;
    const int4 f = *reinterpret_cast<const int4*>(mx + (size_t)y * WW + xb);
    unsigned int mask = 0;
    if (f.x) mask |= 1u;
    if (f.y) mask |= 2u;
    if (f.z) mask |= 4u;
    if (f.w) mask |= 8u;

    const int cnt = __popc(mask);
    int inc = cnt;
#pragma unroll
    for (int off = 1; off < 64; off <<= 1) {
        int n = __shfl_up(inc, off, 64);
        if (lane >= off) inc += n;
    }

    int pos = offsets[rs] + inc - cnt;
    while (mask) {
        int b = __ffs(mask) - 1;
        mask &= mask - 1;
        if (pos < MAXK) { oy[pos] = y; ox[pos] = xb + b; }
        ++pos;
    }
}

// ---------------------------------------------------------------------------
extern "C" void kernel_launch(void* const* d_in, const int* in_sizes, int n_in,
                              void* d_out, int out_size, void* d_ws, size_t ws_size,
                              hipStream_t stream)
{
    const float* rel = (const float*)d_in[0];   // reliability
    const float* rep = (const float*)d_in[1];   // repeatability

    int* out = (int*)d_out;
    int* mx  = out;                       // 4096*4096 maxima (int32 0/1)
    int* oy  = out + (size_t)HH * WW;     // 2^20 y coords
    int* ox  = oy + MAXK;                 // 2^20 x coords

    int* counts  = (int*)d_ws;                        // NRS ints
    int* offsets = counts + NRS;                      // NRS+1 ints (+pad)
    unsigned char* masks = (unsigned char*)(offsets + NRS + 4);  // NRS*64 B

    const size_t need_ws = (size_t)(2 * NRS + 4) * sizeof(int)
                         + (size_t)NRS * 64;
    const bool use_masks = ws_size >= need_ws;

    k_maxima<<<NBLK, 256, 0, stream>>>(rel, rep, mx,
                                       use_masks ? masks : nullptr, counts);
    k_scan<<<1, 1024, 0, stream>>>(counts, offsets);
    if (use_masks)
        k_emit_ws<<<NRS / 4, 256, 0, stream>>>(masks, offsets, oy, ox);
    else
        k_emit_mx<<<NRS / 4, 256, 0, stream>>>(mx, offsets, oy, ox);
}

// Round 9
// 49.702 us; speedup vs baseline: 1.4184x; 1.4184x over previous
//
#include <hip/hip_runtime.h>

#define HH 4096
#define WW 4096
#define MAXK (1 << 20)      // == NRS * 32
#define NSP 8               // 512-px spans per row
#define SPW 512             // span width
#define NRS (HH * NSP)      // 32768 row-spans (1 per wave)
#define NBLK (NRS / 4)      // 8192 blocks, 4 waves each

typedef int   v4i __attribute__((ext_vector_type(4)));
typedef float v4f __attribute__((ext_vector_type(4)));

// ---------------------------------------------------------------------------
// Kernel 1: 3x3 NMS. One WAVE per 512-px row-span, as TWO lane-contiguous
// 256-px panels (8 px/lane). Shuffle halo (panel boundary via lane63<->lane0
// broadcasts), 3 broadcast scalar loads for span-edge columns. No LDS, no
// barriers. Clamp-to-edge == -inf SAME padding for a max filter.
// XCD swizzle: 1024 consecutive blocks (512 rows) per XCD.
// ---------------------------------------------------------------------------
__global__ __launch_bounds__(256, 8) void k_maxima(
    const float* __restrict__ rel, const float* __restrict__ rep,
    int* __restrict__ mx, unsigned char* __restrict__ masks,
    int* __restrict__ counts)
{
    const int tid  = threadIdx.x;
    const int lane = tid & 63;
    const int swz  = (blockIdx.x & 7) * (NBLK / 8) + (blockIdx.x >> 3);
    const int rs   = swz * 4 + (tid >> 6);     // row-span id, 0..NRS-1
    const int y    = rs >> 3;
    const int span = rs & (NSP - 1);
    const int c0   = span * SPW + lane * 4;    // panel-0 column
    const int c1   = c0 + 256;                 // panel-1 column

    const int xl = span ? span * SPW - 1 : 0;                    // left halo col
    const int xr = (span < NSP - 1) ? (span + 1) * SPW : WW - 1; // right halo col
    const int hx = (lane == 63) ? xr : xl;     // 2 cache lines, broadcast

    const float* rowC = rep + (size_t)y * WW;
    const float* rowU = rep + (size_t)(y > 0      ? y - 1 : 0     ) * WW;
    const float* rowD = rep + (size_t)(y < HH - 1 ? y + 1 : HH - 1) * WW;
    const float* rowV = rel + (size_t)y * WW;

    const v4f U0 = *(const v4f*)(rowU + c0), U1 = *(const v4f*)(rowU + c1);
    const v4f C0 = *(const v4f*)(rowC + c0), C1 = *(const v4f*)(rowC + c1);
    const v4f D0 = *(const v4f*)(rowD + c0), D1 = *(const v4f*)(rowD + c1);
    const v4f V0 = *(const v4f*)(rowV + c0), V1 = *(const v4f*)(rowV + c1);
    const float hu = rowU[hx], hc = rowC[hx], hd = rowD[hx];
    const float hvm = fmaxf(fmaxf(hu, hc), hd);

    // vertical 3-max, both panels
    const float a0 = fmaxf(fmaxf(U0.x, C0.x), D0.x);
    const float a1 = fmaxf(fmaxf(U0.y, C0.y), D0.y);
    const float a2 = fmaxf(fmaxf(U0.z, C0.z), D0.z);
    const float a3 = fmaxf(fmaxf(U0.w, C0.w), D0.w);
    const float b0 = fmaxf(fmaxf(U1.x, C1.x), D1.x);
    const float b1 = fmaxf(fmaxf(U1.y, C1.y), D1.y);
    const float b2 = fmaxf(fmaxf(U1.z, C1.z), D1.z);
    const float b3 = fmaxf(fmaxf(U1.w, C1.w), D1.w);

    // horizontal halos
    float l0 = __shfl_up(a3, 1, 64);
    float r0 = __shfl_down(a0, 1, 64);
    float l1 = __shfl_up(b3, 1, 64);
    float r1 = __shfl_down(b0, 1, 64);
    const float b0c = __shfl(b0, 0, 64);    // panel1 lane0 vm -> panel0 lane63 right
    const float a3c = __shfl(a3, 63, 64);   // panel0 lane63 vm -> panel1 lane0 left
    if (lane == 0)  { l0 = hvm;  l1 = a3c; }
    if (lane == 63) { r0 = b0c;  r1 = hvm; }

    unsigned int m0 = 0, m1 = 0;
    if (C0.x == fmaxf(fmaxf(l0, a0), a1) && C0.x >= 0.7f && V0.x >= 0.7f) m0 |= 1u;
    if (C0.y == fmaxf(fmaxf(a0, a1), a2) && C0.y >= 0.7f && V0.y >= 0.7f) m0 |= 2u;
    if (C0.z == fmaxf(fmaxf(a1, a2), a3) && C0.z >= 0.7f && V0.z >= 0.7f) m0 |= 4u;
    if (C0.w == fmaxf(fmaxf(a2, a3), r0) && C0.w >= 0.7f && V0.w >= 0.7f) m0 |= 8u;
    if (C1.x == fmaxf(fmaxf(l1, b0), b1) && C1.x >= 0.7f && V1.x >= 0.7f) m1 |= 1u;
    if (C1.y == fmaxf(fmaxf(b0, b1), b2) && C1.y >= 0.7f && V1.y >= 0.7f) m1 |= 2u;
    if (C1.z == fmaxf(fmaxf(b1, b2), b3) && C1.z >= 0.7f && V1.z >= 0.7f) m1 |= 4u;
    if (C1.w == fmaxf(fmaxf(b2, b3), r1) && C1.w >= 0.7f && V1.w >= 0.7f) m1 |= 8u;

    // maxima as int32 0/1, lane-contiguous, nontemporal (write-once)
    v4i o;
    o.x = m0 & 1u; o.y = (m0 >> 1) & 1u; o.z = (m0 >> 2) & 1u; o.w = (m0 >> 3) & 1u;
    __builtin_nontemporal_store(o, reinterpret_cast<v4i*>(mx + (size_t)y * WW + c0));
    o.x = m1 & 1u; o.y = (m1 >> 1) & 1u; o.z = (m1 >> 2) & 1u; o.w = (m1 >> 3) & 1u;
    __builtin_nontemporal_store(o, reinterpret_cast<v4i*>(mx + (size_t)y * WW + c1));

    if (masks) masks[(size_t)rs * 64 + lane] = (unsigned char)(m0 | (m1 << 4));

    int cnt = __popc(m0 | (m1 << 4));
#pragma unroll
    for (int off = 32; off; off >>= 1) cnt += __shfl_down(cnt, off, 64);
    if (lane == 0) counts[rs] = cnt;
}

// ---------------------------------------------------------------------------
// Kernel 2: exclusive scan of 32768 span counts. One block, 1024 threads,
// 32 counts/thread. offsets[NRS] = total.
// ---------------------------------------------------------------------------
__global__ __launch_bounds__(1024) void k_scan(const int* __restrict__ counts,
                                               int* __restrict__ offsets)
{
    const int tid  = threadIdx.x;
    const int lane = tid & 63, wid = tid >> 6;   // 16 waves

    int v[32];
    int tot = 0;
    const int4* src = reinterpret_cast<const int4*>(counts + tid * 32);
#pragma unroll
    for (int i = 0; i < 8; ++i) {
        int4 a = src[i];
        v[4 * i] = a.x; v[4 * i + 1] = a.y; v[4 * i + 2] = a.z; v[4 * i + 3] = a.w;
        tot += a.x + a.y + a.z + a.w;
    }

    int inc = tot;
#pragma unroll
    for (int off = 1; off < 64; off <<= 1) {
        int n = __shfl_up(inc, off, 64);
        if (lane >= off) inc += n;
    }
    __shared__ int wsum[16];
    if (lane == 63) wsum[wid] = inc;
    __syncthreads();
    int wbase = 0;
    for (int w = 0; w < wid; ++w) wbase += wsum[w];

    int run = wbase + inc - tot;
    int4* dst = reinterpret_cast<int4*>(offsets + tid * 32);
#pragma unroll
    for (int i = 0; i < 8; ++i) {
        int4 o;
        o.x = run; run += v[4 * i];
        o.y = run; run += v[4 * i + 1];
        o.z = run; run += v[4 * i + 2];
        o.w = run; run += v[4 * i + 3];
        dst[i] = o;
    }
    if (tid == 1023) offsets[NRS] = run;   // total keypoint count
}

// ---------------------------------------------------------------------------
// Kernel 3a: ordered compaction, one WAVE per 512-px row-span. Two-panel
// ordered prefix via packed 16+16-bit scan. Fused -1 tail fill: span rs owns
// coord slots [rs*32, rs*32+32).
// ---------------------------------------------------------------------------
__global__ __launch_bounds__(256) void k_emit_ws(
    const unsigned char* __restrict__ masks, const int* __restrict__ offsets,
    int* __restrict__ oy, int* __restrict__ ox)
{
    const int tid  = threadIdx.x;
    const int lane = tid & 63;
    const int rs   = blockIdx.x * 4 + (tid >> 6);

    const int total = offsets[NRS];
    if (lane < 32) {
        const int slot = rs * 32 + lane;
        if (slot >= total) { oy[slot] = -1; ox[slot] = -1; }
    }

    const unsigned int b = masks[(size_t)rs * 64 + lane];
    unsigned int m0 = b & 0xFu, m1 = b >> 4;
    const int cnt0 = __popc(m0), cnt1 = __popc(m1);

    int inc = cnt0 | (cnt1 << 16);
#pragma unroll
    for (int off = 1; off < 64; off <<= 1) {
        int n = __shfl_up(inc, off, 64);
        if (lane >= off) inc += n;
    }
    const int tot0 = __shfl(inc, 63, 64) & 0xFFFF;
    const int base = offsets[rs];
    const int y    = rs >> 3;
    const int xb   = (rs & (NSP - 1)) * SPW + lane * 4;

    int pos = base + (inc & 0xFFFF) - cnt0;          // panel 0
    while (m0) {
        int bit = __ffs(m0) - 1;
        m0 &= m0 - 1;
        if (pos < MAXK) { oy[pos] = y; ox[pos] = xb + bit; }
        ++pos;
    }
    pos = base + tot0 + (inc >> 16) - cnt1;          // panel 1
    while (m1) {
        int bit = __ffs(m1) - 1;
        m1 &= m1 - 1;
        if (pos < MAXK) { oy[pos] = y; ox[pos] = xb + 256 + bit; }
        ++pos;
    }
}

// ---------------------------------------------------------------------------
// Kernel 3b: fallback — rebuild masks from the int32 maxima array.
// ---------------------------------------------------------------------------
__global__ __launch_bounds__(256) void k_emit_mx(
    const int* __restrict__ mx, const int* __restrict__ offsets,
    int* __restrict__ oy, int* __restrict__ ox)
{
    const int tid  = threadIdx.x;
    const int lane = tid & 63;
    const int rs   = blockIdx.x * 4 + (tid >> 6);
    const int y    = rs >> 3;
    const int xb   = (rs & (NSP - 1)) * SPW + lane * 4;

    const int total = offsets[NRS];
    if (lane < 32) {
        const int slot = rs * 32 + lane;
        if (slot >= total) { oy[slot] = -1; ox[slot] = -1; }
    }

    const int4 f0 = *reinterpret_cast<const int4*>(mx + (size_t)y * WW + xb);
    const int4 f1 = *reinterpret_cast<const int4*>(mx + (size_t)y * WW + xb + 256);
    unsigned int m0 = 0, m1 = 0;
    if (f0.x) m0 |= 1u;  if (f0.y) m0 |= 2u;  if (f0.z) m0 |= 4u;  if (f0.w) m0 |= 8u;
    if (f1.x) m1 |= 1u;  if (f1.y) m1 |= 2u;  if (f1.z) m1 |= 4u;  if (f1.w) m1 |= 8u;
    const int cnt0 = __popc(m0), cnt1 = __popc(m1);

    int inc = cnt0 | (cnt1 << 16);
#pragma unroll
    for (int off = 1; off < 64; off <<= 1) {
        int n = __shfl_up(inc, off, 64);
        if (lane >= off) inc += n;
    }
    const int tot0 = __shfl(inc, 63, 64) & 0xFFFF;
    const int base = offsets[rs];

    int pos = base + (inc & 0xFFFF) - cnt0;
    while (m0) {
        int bit = __ffs(m0) - 1;
        m0 &= m0 - 1;
        if (pos < MAXK) { oy[pos] = y; ox[pos] = xb + bit; }
        ++pos;
    }
    pos = base + tot0 + (inc >> 16) - cnt1;
    while (m1) {
        int bit = __ffs(m1) - 1;
        m1 &= m1 - 1;
        if (pos < MAXK) { oy[pos] = y; ox[pos] = xb + 256 + bit; }
        ++pos;
    }
}

// ---------------------------------------------------------------------------
extern "C" void kernel_launch(void* const* d_in, const int* in_sizes, int n_in,
                              void* d_out, int out_size, void* d_ws, size_t ws_size,
                              hipStream_t stream)
{
    const float* rel = (const float*)d_in[0];   // reliability
    const float* rep = (const float*)d_in[1];   // repeatability

    int* out = (int*)d_out;
    int* mx  = out;                       // 4096*4096 maxima (int32 0/1)
    int* oy  = out + (size_t)HH * WW;     // 2^20 y coords
    int* ox  = oy + MAXK;                 // 2^20 x coords

    int* counts  = (int*)d_ws;                        // NRS ints
    int* offsets = counts + NRS;                      // NRS+1 ints (+pad)
    unsigned char* masks = (unsigned char*)(offsets + NRS + 4);  // NRS*64 B

    const size_t need_ws = (size_t)(2 * NRS + 4) * sizeof(int)
                         + (size_t)NRS * 64;
    const bool use_masks = ws_size >= need_ws;

    k_maxima<<<NBLK, 256, 0, stream>>>(rel, rep, mx,
                                       use_masks ? masks : nullptr, counts);
    k_scan<<<1, 1024, 0, stream>>>(counts, offsets);
    if (use_masks)
        k_emit_ws<<<NRS / 4, 256, 0, stream>>>(masks, offsets, oy, ox);
    else
        k_emit_mx<<<NRS / 4, 256, 0, stream>>>(mx, offsets, oy, ox);
}